// Round 1
// baseline (953.760 us; speedup 1.0000x reference)
//
#include <hip/hip_runtime.h>
#include <math.h>

#define BB 64
#define LL 200
#define DD 300
#define PP 16
#define EPSV 1e-12f

#define TI 64
#define TJ 64
#define TK 16
#define TIP 68   // padded leading dim: 68*4=272 B, multiple of 16 -> float4-aligned LDS rows

// ---------------- norms: n_inv[b,row,p] = 1/sqrt(max(sum_d (s_d * k_pd)^2, eps)) ----------
__global__ __launch_bounds__(256) void norms_kernel(const float* __restrict__ s1,
                                                    const float* __restrict__ s2,
                                                    const float* __restrict__ kern,
                                                    float* __restrict__ n1inv,
                                                    float* __restrict__ n2inv) {
    // grid: (LL, 2, BB), block 256
    const int row   = blockIdx.x;
    const int which = blockIdx.y;
    const int b     = blockIdx.z;
    const float* s  = which ? s2 : s1;
    float* outp     = which ? n2inv : n1inv;

    __shared__ float rowbuf[DD];
    const int t = threadIdx.x;
    for (int d = t; d < DD; d += 256) rowbuf[d] = s[(size_t)(b * LL + row) * DD + d];
    __syncthreads();

    const int p = t >> 4;   // 0..15
    const int g = t & 15;   // 0..15
    float acc = 0.f;
    for (int d = g; d < DD; d += 16) {
        float v = rowbuf[d] * kern[p * DD + d];
        acc += v * v;
    }
    // reduce within groups of 16 lanes (groups aligned inside the 64-lane wave)
    acc += __shfl_xor(acc, 1);
    acc += __shfl_xor(acc, 2);
    acc += __shfl_xor(acc, 4);
    acc += __shfl_xor(acc, 8);
    if (g == 0) outp[(size_t)(b * LL + row) * PP + p] = 1.0f / sqrtf(fmaxf(acc, EPSV));
}

// ---------------- main: per (b,p,i-tile): C[i,j] = sum_d s1[i,d]*s2[j,d]*ksq[d]*n2inv[j]
//                  out[b,i,p] = n1inv[b,i,p] * max_j C[i,j] --------------------------------
__global__ __launch_bounds__(256) void maxsim_kernel(const float* __restrict__ s1,
                                                     const float* __restrict__ s2,
                                                     const float* __restrict__ kern,
                                                     const float* __restrict__ n1inv,
                                                     const float* __restrict__ n2inv,
                                                     float* __restrict__ out) {
    // grid: (4 i-tiles, PP, BB), block 256
    const int it = blockIdx.x;
    const int p  = blockIdx.y;
    const int b  = blockIdx.z;
    const int i0 = it * TI;

    __shared__ float As[TK][TIP];
    __shared__ float Bs[TK][TIP];
    __shared__ float ksq[DD];
    __shared__ float n2s[TJ];
    __shared__ float smax[TI][17];

    const int t  = threadIdx.x;
    const int tx = t & 15;
    const int ty = t >> 4;

    // preload squared kernel row for this p
    for (int d = t; d < DD; d += 256) {
        float kv = kern[p * DD + d];
        ksq[d] = kv * kv;
    }

    const float* s1base = s1 + (size_t)(b * LL) * DD;
    const float* s2base = s2 + (size_t)(b * LL) * DD;

    float rmax[4] = {-INFINITY, -INFINITY, -INFINITY, -INFINITY};

    for (int j0 = 0; j0 < LL; j0 += TJ) {
        __syncthreads();  // ksq ready (first iter); n2s from prev iter no longer needed
        if (t < TJ) {
            int j = j0 + t;
            n2s[t] = (j < LL) ? n2inv[(size_t)(b * LL + j) * PP + p] : 0.f;
        }

        float acc[4][4];
#pragma unroll
        for (int r = 0; r < 4; r++)
#pragma unroll
            for (int c = 0; c < 4; c++) acc[r][c] = 0.f;

        for (int k0 = 0; k0 < DD; k0 += TK) {
            __syncthreads();  // previous compute done before overwriting As/Bs
            // stage 64x16 A-tile and weighted B-tile, k-major in LDS
#pragma unroll
            for (int q = 0; q < 4; q++) {
                int n  = t + q * 256;
                int ii = n >> 4;    // 0..63
                int kk = n & 15;    // 0..15
                int d  = k0 + kk;
                float av = 0.f, bv = 0.f;
                if (d < DD) {
                    int gi = i0 + ii;
                    if (gi < LL) av = s1base[(size_t)gi * DD + d];
                    int gj = j0 + ii;
                    if (gj < LL) bv = s2base[(size_t)gj * DD + d] * ksq[d] * n2s[ii];
                }
                As[kk][ii] = av;
                Bs[kk][ii] = bv;
            }
            __syncthreads();

#pragma unroll
            for (int kk = 0; kk < TK; kk++) {
                float4 a4 = *(const float4*)&As[kk][ty * 4];
                float4 b4 = *(const float4*)&Bs[kk][tx * 4];
                float av[4] = {a4.x, a4.y, a4.z, a4.w};
                float bv[4] = {b4.x, b4.y, b4.z, b4.w};
#pragma unroll
                for (int r = 0; r < 4; r++)
#pragma unroll
                    for (int c = 0; c < 4; c++)
                        acc[r][c] = fmaf(av[r], bv[c], acc[r][c]);
            }
        }

        // fold this j-tile into running max (only valid j columns)
#pragma unroll
        for (int c = 0; c < 4; c++) {
            int j = j0 + tx * 4 + c;
            if (j < LL) {
#pragma unroll
                for (int r = 0; r < 4; r++) rmax[r] = fmaxf(rmax[r], acc[r][c]);
            }
        }
    }

    // cross-thread max over tx, then scale by n1inv and store
    __syncthreads();
#pragma unroll
    for (int r = 0; r < 4; r++) smax[ty * 4 + r][tx] = rmax[r];
    __syncthreads();

    if (t < TI) {
        int i = i0 + t;
        if (i < LL) {
            float m = -INFINITY;
#pragma unroll
            for (int x = 0; x < 16; x++) m = fmaxf(m, smax[t][x]);
            out[(size_t)(b * LL + i) * PP + p] = m * n1inv[(size_t)(b * LL + i) * PP + p];
        }
    }
}

extern "C" void kernel_launch(void* const* d_in, const int* in_sizes, int n_in,
                              void* d_out, int out_size, void* d_ws, size_t ws_size,
                              hipStream_t stream) {
    const float* sent1  = (const float*)d_in[0];   // (64,200,300) f32
    const float* sent2  = (const float*)d_in[1];   // (64,200,300) f32
    const float* kernel = (const float*)d_in[2];   // (16,300)     f32
    float* out = (float*)d_out;                    // (64,200,16)  f32

    float* n1inv = (float*)d_ws;                   // BB*LL*PP floats
    float* n2inv = n1inv + (size_t)BB * LL * PP;   // BB*LL*PP floats

    dim3 ngrid(LL, 2, BB);
    norms_kernel<<<ngrid, 256, 0, stream>>>(sent1, sent2, kernel, n1inv, n2inv);

    dim3 mgrid((LL + TI - 1) / TI, PP, BB);
    maxsim_kernel<<<mgrid, 256, 0, stream>>>(sent1, sent2, kernel, n1inv, n2inv, out);
}

// Round 2
// 283.258 us; speedup vs baseline: 3.3671x; 3.3671x over previous
//
#include <hip/hip_runtime.h>
#include <math.h>

#define BB 64
#define LL 200
#define DD 300
#define PP 16
#define EPSV 1e-12f

#define TIB 64     // i rows per block
#define TJB 256    // padded j per block (covers all 200)
#define KC  32     // k chunk (one MFMA K-step)
#define KPAD 320   // padded K
#define LDK 40     // LDS row stride in halfs (80 B, 16B-aligned, 2-way bank alias = free)

typedef _Float16 f16x8 __attribute__((ext_vector_type(8)));
typedef _Float16 f16x4 __attribute__((ext_vector_type(4)));
typedef float f32x4v __attribute__((ext_vector_type(4)));

// ---------------- norms: n_inv[b,row,p] = 1/sqrt(max(sum_d (s_d*k_pd)^2, eps)) ----------
__global__ __launch_bounds__(256) void norms_kernel(const float* __restrict__ s1,
                                                    const float* __restrict__ s2,
                                                    const float* __restrict__ kern,
                                                    float* __restrict__ n1inv,
                                                    float* __restrict__ n2inv) {
    const int row   = blockIdx.x;
    const int which = blockIdx.y;
    const int b     = blockIdx.z;
    const float* s  = which ? s2 : s1;
    float* outp     = which ? n2inv : n1inv;

    __shared__ float rowbuf[DD];
    const int t = threadIdx.x;
    for (int d = t; d < DD; d += 256) rowbuf[d] = s[(size_t)(b * LL + row) * DD + d];
    __syncthreads();

    const int p = t >> 4;
    const int g = t & 15;
    float acc = 0.f;
    for (int d = g; d < DD; d += 16) {
        float v = rowbuf[d] * kern[p * DD + d];
        acc += v * v;
    }
    acc += __shfl_xor(acc, 1);
    acc += __shfl_xor(acc, 2);
    acc += __shfl_xor(acc, 4);
    acc += __shfl_xor(acc, 8);
    if (g == 0) outp[(size_t)(b * LL + row) * PP + p] = 1.0f / sqrtf(fmaxf(acc, EPSV));
}

// ---------------- maxsim via f16 MFMA ---------------------------------------------------
// block: (i-tile, p, b). A[i,k]=s1[i,k]*kp[k]*n1inv[i]; B[j,k]=s2[j,k]*kp[k]*n2inv[j]
// C[i,j] = A·B^T accumulated in fp32 MFMA; out = max_j C (both norms pre-folded).
__global__ __launch_bounds__(256) void maxsim_kernel(const float* __restrict__ s1,
                                                     const float* __restrict__ s2,
                                                     const float* __restrict__ kern,
                                                     const float* __restrict__ n1inv,
                                                     const float* __restrict__ n2inv,
                                                     float* __restrict__ out) {
    const int it_blk = blockIdx.x;
    const int p      = blockIdx.y;
    const int b      = blockIdx.z;
    const int i0     = it_blk * TIB;

    __shared__ _Float16 As[TIB][LDK];    // 5120 B
    __shared__ _Float16 Bs[TJB][LDK];    // 20480 B
    __shared__ float kp[KPAD];           // 1280 B
    __shared__ float n1s[TIB];
    __shared__ float n2s[TJB];
    __shared__ float smax[TIB][5];

    const int t = threadIdx.x;

    // preload kernel row (zero-padded) and the inverse norms
    for (int d = t; d < KPAD; d += 256) kp[d] = (d < DD) ? kern[p * DD + d] : 0.f;
    if (t < TIB) {
        int i = i0 + t;
        n1s[t] = (i < LL) ? n1inv[(size_t)(b * LL + i) * PP + p] : 0.f;
    }
    {
        int j = t;
        n2s[t] = (j < LL) ? n2inv[(size_t)(b * LL + j) * PP + p] : 0.f;
    }

    const float* s1base = s1 + (size_t)(b * LL) * DD;
    const float* s2base = s2 + (size_t)(b * LL) * DD;

    f32x4v acc[4][4];
#pragma unroll
    for (int it = 0; it < 4; it++)
#pragma unroll
        for (int jt = 0; jt < 4; jt++) acc[it][jt] = (f32x4v)0.f;

    const int rq = t & 7;    // float4 slot within 32-k chunk
    const int rr = t >> 3;   // 0..31 row group
    const int w    = t >> 6;   // wave 0..3 -> j-slab [64w, 64w+64)
    const int lane = t & 63;
    const int c    = lane & 15;
    const int quad = lane >> 4;

    __syncthreads();  // kp/n1s/n2s ready

    for (int k0 = 0; k0 < KPAD; k0 += KC) {
        const int kk = k0 + rq * 4;
        const bool kvalid = (kk < DD);   // DD%4==0, so full float4 valid iff kk<DD
        float4 kp4 = *(const float4*)&kp[kk];  // always in-bounds (KPAD)

        // stage A: 64 rows x 32 k
#pragma unroll
        for (int rep = 0; rep < 2; rep++) {
            int i  = rr + rep * 32;
            int gi = i0 + i;
            float4 s4 = make_float4(0.f, 0.f, 0.f, 0.f);
            if (kvalid && gi < LL) s4 = *(const float4*)&s1base[(size_t)gi * DD + kk];
            float sc = n1s[i];
            f16x4 h;
            h[0] = (_Float16)(s4.x * kp4.x * sc);
            h[1] = (_Float16)(s4.y * kp4.y * sc);
            h[2] = (_Float16)(s4.z * kp4.z * sc);
            h[3] = (_Float16)(s4.w * kp4.w * sc);
            *(f16x4*)&As[i][rq * 4] = h;
        }
        // stage B: 256 rows x 32 k
#pragma unroll
        for (int rep = 0; rep < 8; rep++) {
            int j = rr + rep * 32;
            float4 s4 = make_float4(0.f, 0.f, 0.f, 0.f);
            if (kvalid && j < LL) s4 = *(const float4*)&s2base[(size_t)j * DD + kk];
            float sc = n2s[j];
            f16x4 h;
            h[0] = (_Float16)(s4.x * kp4.x * sc);
            h[1] = (_Float16)(s4.y * kp4.y * sc);
            h[2] = (_Float16)(s4.z * kp4.z * sc);
            h[3] = (_Float16)(s4.w * kp4.w * sc);
            *(f16x4*)&Bs[j][rq * 4] = h;
        }
        __syncthreads();

        // fragments: A[m=lane&15][k=quad*8+j], B likewise (both k-contiguous rows)
        f16x8 af[4], bf[4];
#pragma unroll
        for (int it = 0; it < 4; it++)
            af[it] = *(const f16x8*)&As[it * 16 + c][quad * 8];
#pragma unroll
        for (int jt = 0; jt < 4; jt++)
            bf[jt] = *(const f16x8*)&Bs[w * 64 + jt * 16 + c][quad * 8];

#pragma unroll
        for (int it = 0; it < 4; it++)
#pragma unroll
            for (int jt = 0; jt < 4; jt++)
                acc[it][jt] = __builtin_amdgcn_mfma_f32_16x16x32_f16(af[it], bf[jt], acc[it][jt], 0, 0, 0);

        __syncthreads();  // compute done before next chunk overwrites As/Bs
    }

    // fold: max over this wave's valid j columns (C/D: col=lane&15, row=quad*4+reg)
    float rmax[4][4];
#pragma unroll
    for (int it = 0; it < 4; it++)
#pragma unroll
        for (int r = 0; r < 4; r++) rmax[it][r] = -INFINITY;

#pragma unroll
    for (int jt = 0; jt < 4; jt++) {
        int j = w * 64 + jt * 16 + c;
        if (j < LL) {
#pragma unroll
            for (int it = 0; it < 4; it++)
#pragma unroll
                for (int r = 0; r < 4; r++)
                    rmax[it][r] = fmaxf(rmax[it][r], acc[it][jt][r]);
        }
    }
    // reduce across the 16 columns held by the quad's lanes
#pragma unroll
    for (int m = 1; m <= 8; m <<= 1) {
#pragma unroll
        for (int it = 0; it < 4; it++)
#pragma unroll
            for (int r = 0; r < 4; r++)
                rmax[it][r] = fmaxf(rmax[it][r], __shfl_xor(rmax[it][r], m));
    }

    if (c == 0) {
#pragma unroll
        for (int it = 0; it < 4; it++)
#pragma unroll
            for (int r = 0; r < 4; r++)
                smax[it * 16 + quad * 4 + r][w] = rmax[it][r];
    }
    __syncthreads();

    if (t < TIB) {
        int i = i0 + t;
        if (i < LL) {
            float m = fmaxf(fmaxf(smax[t][0], smax[t][1]), fmaxf(smax[t][2], smax[t][3]));
            out[(size_t)(b * LL + i) * PP + p] = m;
        }
    }
}

extern "C" void kernel_launch(void* const* d_in, const int* in_sizes, int n_in,
                              void* d_out, int out_size, void* d_ws, size_t ws_size,
                              hipStream_t stream) {
    const float* sent1  = (const float*)d_in[0];   // (64,200,300) f32
    const float* sent2  = (const float*)d_in[1];   // (64,200,300) f32
    const float* kernel = (const float*)d_in[2];   // (16,300)     f32
    float* out = (float*)d_out;                    // (64,200,16)  f32

    float* n1inv = (float*)d_ws;                   // BB*LL*PP floats
    float* n2inv = n1inv + (size_t)BB * LL * PP;   // BB*LL*PP floats

    dim3 ngrid(LL, 2, BB);
    norms_kernel<<<ngrid, 256, 0, stream>>>(sent1, sent2, kernel, n1inv, n2inv);

    dim3 mgrid((LL + TIB - 1) / TIB, PP, BB);
    maxsim_kernel<<<mgrid, 256, 0, stream>>>(sent1, sent2, kernel, n1inv, n2inv, out);
}

// Round 3
// 219.771 us; speedup vs baseline: 4.3398x; 1.2889x over previous
//
#include <hip/hip_runtime.h>
#include <math.h>

#define BBATCH 64
#define LL 200
#define DD 300
#define PP 16
#define EPSV 1e-12f
#define KPAD 320
#define NCHUNK 10

typedef _Float16 f16x8 __attribute__((ext_vector_type(8)));
typedef float f32x4v __attribute__((ext_vector_type(4)));

__device__ __forceinline__ int swz(int r) { return (r ^ (r >> 2)) & 3; }

// ---------------- norms: n_inv[b,row,p] = 1/sqrt(max(sum_d (s_d*k_pd)^2, eps)) ----------
// 8 rows per block; kern slice held in registers; rows staged once in LDS.
__global__ __launch_bounds__(256) void norms_kernel(const float* __restrict__ s1,
                                                    const float* __restrict__ s2,
                                                    const float* __restrict__ kern,
                                                    float* __restrict__ n1inv,
                                                    float* __restrict__ n2inv) {
    const int chunk = blockIdx.x;   // 25
    const int which = blockIdx.y;   // 2
    const int b     = blockIdx.z;   // 64
    const float* s  = which ? s2 : s1;
    float* outp     = which ? n2inv : n1inv;
    const int r0    = chunk * 8;

    __shared__ float rows[8][304];
    const int t = threadIdx.x;
    const int p = t >> 4;
    const int g = t & 15;

#pragma unroll
    for (int rr = 0; rr < 8; rr++) {
        const float* src = s + (size_t)(b * LL + r0 + rr) * DD;
        for (int d = t; d < 304; d += 256) rows[rr][d] = (d < DD) ? src[d] : 0.f;
    }
    float kreg[19];
#pragma unroll
    for (int m = 0; m < 19; m++) {
        int k = g + 16 * m;
        kreg[m] = (k < DD) ? kern[p * DD + k] : 0.f;
    }
    __syncthreads();

#pragma unroll
    for (int rr = 0; rr < 8; rr++) {
        float acc = 0.f;
#pragma unroll
        for (int m = 0; m < 19; m++) {
            float v = rows[rr][g + 16 * m] * kreg[m];
            acc += v * v;
        }
        acc += __shfl_xor(acc, 1);
        acc += __shfl_xor(acc, 2);
        acc += __shfl_xor(acc, 4);
        acc += __shfl_xor(acc, 8);
        if (g == 0) outp[(size_t)(b * LL + r0 + rr) * PP + p] = 1.0f / sqrtf(fmaxf(acc, EPSV));
    }
}

// ---------------- maxsim: per (b,p): C = A·B^T with A=f16(s1), B=f16(s2*kp^2*n2inv) ------
// block tile 128i x 128j; 4 waves (2x2), wave tile 64x64; double-buffered swizzled LDS;
// writes per-jblk partial max to ws (n1inv applied in reduce pass).
__global__ __launch_bounds__(256, 3) void maxsim_kernel(const float* __restrict__ s1,
                                                        const float* __restrict__ s2,
                                                        const float* __restrict__ kern,
                                                        const float* __restrict__ n2inv,
                                                        float* __restrict__ part) {
    const int iblk = blockIdx.x >> 1;
    const int jblk = blockIdx.x & 1;
    const int p    = blockIdx.y;
    const int b    = blockIdx.z;
    const int i0   = iblk * 128;
    const int j0   = jblk * 128;

    __shared__ __align__(16) _Float16 As[2][128 * 32];   // 16 KB
    __shared__ __align__(16) _Float16 Bs[2][128 * 32];   // 16 KB
    __shared__ float ksq[KPAD];
    __shared__ float n2s[128];
    __shared__ float smax[128][2];

    const int t = threadIdx.x;
    const float* s1b = s1 + (size_t)b * LL * DD;
    const float* s2b = s2 + (size_t)b * LL * DD;

    for (int d = t; d < KPAD; d += 256) {
        float kv = (d < DD) ? kern[p * DD + d] : 0.f;
        ksq[d] = kv * kv;
    }
    if (t < 128) {
        int j = j0 + t;
        n2s[t] = (j < LL) ? n2inv[(size_t)(b * LL + j) * PP + p] : 0.f;
    }
    __syncthreads();

    float pa[2][8], pb[2][8];

    auto loadg = [&](int k0) {
#pragma unroll
        for (int q = 0; q < 2; q++) {
            int n = t + q * 256;
            int r = n >> 2;
            int g = n & 3;
            int k = k0 + g * 8;
            int gi = i0 + r;
            if (gi < LL && k + 8 <= DD) {
                float4 u = *(const float4*)&s1b[(size_t)gi * DD + k];
                float4 v = *(const float4*)&s1b[(size_t)gi * DD + k + 4];
                pa[q][0] = u.x; pa[q][1] = u.y; pa[q][2] = u.z; pa[q][3] = u.w;
                pa[q][4] = v.x; pa[q][5] = v.y; pa[q][6] = v.z; pa[q][7] = v.w;
            } else {
#pragma unroll
                for (int e = 0; e < 8; e++)
                    pa[q][e] = (gi < LL && k + e < DD) ? s1b[(size_t)gi * DD + k + e] : 0.f;
            }
            int gj = j0 + r;
            if (gj < LL && k + 8 <= DD) {
                float4 u = *(const float4*)&s2b[(size_t)gj * DD + k];
                float4 v = *(const float4*)&s2b[(size_t)gj * DD + k + 4];
                pb[q][0] = u.x; pb[q][1] = u.y; pb[q][2] = u.z; pb[q][3] = u.w;
                pb[q][4] = v.x; pb[q][5] = v.y; pb[q][6] = v.z; pb[q][7] = v.w;
            } else {
#pragma unroll
                for (int e = 0; e < 8; e++)
                    pb[q][e] = (gj < LL && k + e < DD) ? s2b[(size_t)gj * DD + k + e] : 0.f;
            }
        }
    };

    auto storeg = [&](int bi, int k0) {
#pragma unroll
        for (int q = 0; q < 2; q++) {
            int n = t + q * 256;
            int r = n >> 2;
            int g = n & 3;
            int k = k0 + g * 8;
            int slot = (g ^ swz(r)) << 3;
            f16x8 ha;
#pragma unroll
            for (int e = 0; e < 8; e++) ha[e] = (_Float16)pa[q][e];
            *(f16x8*)&As[bi][r * 32 + slot] = ha;
            float n2r = n2s[r];
            float4 kq0 = *(const float4*)&ksq[k];
            float4 kq1 = *(const float4*)&ksq[k + 4];
            float kk[8] = {kq0.x, kq0.y, kq0.z, kq0.w, kq1.x, kq1.y, kq1.z, kq1.w};
            f16x8 hb;
#pragma unroll
            for (int e = 0; e < 8; e++) hb[e] = (_Float16)(pb[q][e] * kk[e] * n2r);
            *(f16x8*)&Bs[bi][r * 32 + slot] = hb;
        }
    };

    f32x4v acc[4][4];
#pragma unroll
    for (int it = 0; it < 4; it++)
#pragma unroll
        for (int jt = 0; jt < 4; jt++) acc[it][jt] = (f32x4v)0.f;

    const int lane = t & 63;
    const int w    = t >> 6;
    const int wi   = w >> 1;
    const int wj   = w & 1;
    const int c    = lane & 15;
    const int quad = lane >> 4;

    loadg(0);
    storeg(0, 0);
    int cur = 0;
    for (int kc = 0; kc < NCHUNK; kc++) {
        if (kc < NCHUNK - 1) loadg((kc + 1) * 32);   // prefetch: in flight across compute
        __syncthreads();                             // buf[cur] ready

        f16x8 af[4], bf[4];
#pragma unroll
        for (int it = 0; it < 4; it++) {
            int ar = wi * 64 + it * 16 + c;
            af[it] = *(const f16x8*)&As[cur][ar * 32 + ((quad ^ swz(ar)) << 3)];
        }
#pragma unroll
        for (int jt = 0; jt < 4; jt++) {
            int br = wj * 64 + jt * 16 + c;
            bf[jt] = *(const f16x8*)&Bs[cur][br * 32 + ((quad ^ swz(br)) << 3)];
        }
#pragma unroll
        for (int it = 0; it < 4; it++)
#pragma unroll
            for (int jt = 0; jt < 4; jt++)
                acc[it][jt] = __builtin_amdgcn_mfma_f32_16x16x32_f16(af[it], bf[jt], acc[it][jt], 0, 0, 0);

        if (kc < NCHUNK - 1) storeg(cur ^ 1, (kc + 1) * 32);
        cur ^= 1;
    }

    // fold max over this wave's valid j columns (C/D: col=lane&15, row=quad*4+reg)
    float rmax[4][4];
#pragma unroll
    for (int it = 0; it < 4; it++)
#pragma unroll
        for (int r = 0; r < 4; r++) rmax[it][r] = -INFINITY;

#pragma unroll
    for (int jt = 0; jt < 4; jt++) {
        int jg = j0 + wj * 64 + jt * 16 + c;
        if (jg < LL) {
#pragma unroll
            for (int it = 0; it < 4; it++)
#pragma unroll
                for (int r = 0; r < 4; r++)
                    rmax[it][r] = fmaxf(rmax[it][r], acc[it][jt][r]);
        }
    }
#pragma unroll
    for (int m = 1; m <= 8; m <<= 1) {
#pragma unroll
        for (int it = 0; it < 4; it++)
#pragma unroll
            for (int r = 0; r < 4; r++)
                rmax[it][r] = fmaxf(rmax[it][r], __shfl_xor(rmax[it][r], m));
    }
    if (c == 0) {
#pragma unroll
        for (int it = 0; it < 4; it++)
#pragma unroll
            for (int r = 0; r < 4; r++)
                smax[wi * 64 + it * 16 + quad * 4 + r][wj] = rmax[it][r];
    }
    __syncthreads();

    if (t < 128) {
        // part layout: [jblk][b][i(256)][p(16)]
        part[(size_t)jblk * (BBATCH * 256 * PP) + (size_t)b * (256 * PP) + (size_t)(i0 + t) * PP + p] =
            fmaxf(smax[t][0], smax[t][1]);
    }
}

// ---------------- reduce: out[b,i,p] = n1inv[b,i,p] * max(part0, part1) ------------------
__global__ __launch_bounds__(256) void reduce_kernel(const float* __restrict__ part,
                                                     const float* __restrict__ n1inv,
                                                     float* __restrict__ out) {
    int tid = blockIdx.x * 256 + threadIdx.x;
    if (tid >= BBATCH * LL * PP) return;
    int b   = tid / (LL * PP);
    int rem = tid - b * (LL * PP);          // i*16+p, i<200 -> rem<3200<4096
    float v0 = part[(size_t)b * (256 * PP) + rem];
    float v1 = part[(size_t)(BBATCH * 256 * PP) + (size_t)b * (256 * PP) + rem];
    out[tid] = fmaxf(v0, v1) * n1inv[tid];
}

extern "C" void kernel_launch(void* const* d_in, const int* in_sizes, int n_in,
                              void* d_out, int out_size, void* d_ws, size_t ws_size,
                              hipStream_t stream) {
    const float* sent1  = (const float*)d_in[0];   // (64,200,300) f32
    const float* sent2  = (const float*)d_in[1];   // (64,200,300) f32
    const float* kernel = (const float*)d_in[2];   // (16,300)     f32
    float* out = (float*)d_out;                    // (64,200,16)  f32

    float* n1inv = (float*)d_ws;                            // 204800 f32
    float* n2inv = n1inv + (size_t)BBATCH * LL * PP;        // 204800 f32
    float* part  = n2inv + (size_t)BBATCH * LL * PP;        // 2*64*256*16 f32 = 2.1 MB

    norms_kernel<<<dim3(25, 2, BBATCH), 256, 0, stream>>>(sent1, sent2, kernel, n1inv, n2inv);
    maxsim_kernel<<<dim3(4, PP, BBATCH), 256, 0, stream>>>(sent1, sent2, kernel, n2inv, part);

    int nout = BBATCH * LL * PP;
    reduce_kernel<<<(nout + 255) / 256, 256, 0, stream>>>(part, n1inv, out);
}